// Round 1
// baseline (88.465 us; speedup 1.0000x reference)
//
#include <hip/hip_runtime.h>

// GAE-style reverse-scan:
//   delta[t]   = rewards[t] + 0.99*0.05*values[t+1]
//   returns[t] = delta[t] + 0.9405*returns[t+1],  returns[T] = 0
// Shapes: rewards/values [1025, 32768] f32, out [1024, 32768] f32.
// One thread per column; double-buffered register prefetch of U=16 timesteps.

#define T_STEPS 1024
#define BATCH   32768
#define UNR     16

__global__ __launch_bounds__(64) void gae_kernel(const float* __restrict__ rewards,
                                                 const float* __restrict__ values,
                                                 float* __restrict__ out) {
    const int b = blockIdx.x * 64 + threadIdx.x;

    const float coefK = 0.99f * 0.05f;   // DISCOUNT * (1 - LAMMDA)
    const float coef  = 0.99f * 0.95f;   // DISCOUNT * LAMMDA

    const float* rp = rewards + b;
    const float* vp = values + b;         // values[t+1] -> vp[(t+1)*BATCH]
    float*       op = out + b;

    float rA[UNR], vA[UNR], rB[UNR], vB[UNR];
    float acc = 0.0f;

// Load chunk C (t in [C*UNR, C*UNR+UNR)) into register arrays RR/VV.
// Constant unrolled indices only -> stays in registers (rule #20).
#define LOAD(RR, VV, C)                                                     \
    {                                                                       \
        const int t0_ = (C) * UNR;                                          \
        _Pragma("unroll")                                                   \
        for (int i = 0; i < UNR; ++i) {                                     \
            RR[i] = rp[(size_t)(t0_ + i) * BATCH];                          \
            VV[i] = vp[(size_t)(t0_ + i + 1) * BATCH];                      \
        }                                                                   \
    }

// Consume chunk C in descending t order, storing results.
#define COMPUTE(RR, VV, C)                                                  \
    {                                                                       \
        const int t0_ = (C) * UNR;                                          \
        _Pragma("unroll")                                                   \
        for (int i = UNR - 1; i >= 0; --i) {                                \
            float delta_ = fmaf(coefK, VV[i], RR[i]);                       \
            acc = fmaf(coef, acc, delta_);                                  \
            op[(size_t)(t0_ + i) * BATCH] = acc;                            \
        }                                                                   \
    }

    constexpr int NC = T_STEPS / UNR;  // 64 chunks, even count

    LOAD(rA, vA, NC - 1);
    for (int c = NC - 1; c >= 1; c -= 2) {
        LOAD(rB, vB, c - 1);       // prefetch next chunk while A in flight
        COMPUTE(rA, vA, c);        // waits only on A's loads (counted vmcnt)
        if (c >= 3) LOAD(rA, vA, c - 2);
        COMPUTE(rB, vB, c - 1);
    }

#undef LOAD
#undef COMPUTE
}

extern "C" void kernel_launch(void* const* d_in, const int* in_sizes, int n_in,
                              void* d_out, int out_size, void* d_ws, size_t ws_size,
                              hipStream_t stream) {
    const float* rewards = (const float*)d_in[0];
    const float* values  = (const float*)d_in[1];
    float* out = (float*)d_out;

    const int grid = BATCH / 64;  // 512 blocks of 1 wave -> 2 blocks/CU
    gae_kernel<<<grid, 64, 0, stream>>>(rewards, values, out);
}

// Round 2
// 75.497 us; speedup vs baseline: 1.1718x; 1.1718x over previous
//
#include <hip/hip_runtime.h>

// GAE-style reverse-scan:
//   delta[t]   = rewards[t] + 0.99*0.05*values[t+1]
//   returns[t] = delta[t] + 0.9405*returns[t+1],  returns[T] = 0
// Shapes: rewards/values [1025, 32768] f32, out [1024, 32768] f32.
// One thread per column. UNR=32 double-buffered register prefetch with the
// next chunk's loads interleaved into the current chunk's compute in matching
// descending order (counted-vmcnt friendly). Non-temporal stores keep the
// 128 MB output stream out of L2/L3 so the 256 MB input set stays resident.

#define T_STEPS 1024
#define BATCH   32768
#define UNR     32

__global__ __launch_bounds__(64) void gae_kernel(const float* __restrict__ rewards,
                                                 const float* __restrict__ values,
                                                 float* __restrict__ out) {
    const int b = blockIdx.x * 64 + threadIdx.x;

    const float coefK = 0.99f * 0.05f;   // DISCOUNT * (1 - LAMMDA)
    const float coef  = 0.99f * 0.95f;   // DISCOUNT * LAMMDA

    const float* rp = rewards + b;
    const float* vp = values + b;         // values[t+1] -> vp[(t+1)*BATCH]
    float*       op = out + b;

    float rA[UNR], vA[UNR], rB[UNR], vB[UNR];
    float acc = 0.0f;

// Load full chunk C (descending i, matching later consumption order).
#define PRELOAD(RR, VV, C)                                                  \
    {                                                                       \
        const int t0_ = (C) * UNR;                                          \
        _Pragma("unroll")                                                   \
        for (int i = UNR - 1; i >= 0; --i) {                                \
            RR[i] = rp[(size_t)(t0_ + i) * BATCH];                          \
            VV[i] = vp[(size_t)(t0_ + i + 1) * BATCH];                      \
        }                                                                   \
    }

// Compute chunk C from CUR regs (descending t) while prefetching chunk PC
// into NXT regs, one element per step. All register indices compile-time.
#define STEP(CR, CV, NR, NV, C, PC)                                         \
    {                                                                       \
        const int t0_ = (C) * UNR;                                          \
        const int p0_ = (PC) * UNR;                                         \
        const bool pf_ = (PC) >= 0;                                         \
        _Pragma("unroll")                                                   \
        for (int i = UNR - 1; i >= 0; --i) {                                \
            if (pf_) {                                                      \
                NR[i] = rp[(size_t)(p0_ + i) * BATCH];                      \
                NV[i] = vp[(size_t)(p0_ + i + 1) * BATCH];                  \
            }                                                               \
            float delta_ = fmaf(coefK, CV[i], CR[i]);                       \
            acc = fmaf(coef, acc, delta_);                                  \
            __builtin_nontemporal_store(acc, &op[(size_t)(t0_ + i) * BATCH]); \
        }                                                                   \
    }

    constexpr int NC = T_STEPS / UNR;  // 32 chunks, even count

    PRELOAD(rA, vA, NC - 1);
    for (int c = NC - 1; c >= 1; c -= 2) {
        STEP(rA, vA, rB, vB, c,     c - 1);  // compute A, prefetch into B
        STEP(rB, vB, rA, vA, c - 1, c - 2);  // compute B, prefetch into A
    }

#undef PRELOAD
#undef STEP
}

extern "C" void kernel_launch(void* const* d_in, const int* in_sizes, int n_in,
                              void* d_out, int out_size, void* d_ws, size_t ws_size,
                              hipStream_t stream) {
    const float* rewards = (const float*)d_in[0];
    const float* values  = (const float*)d_in[1];
    float* out = (float*)d_out;

    const int grid = BATCH / 64;  // 512 blocks of 1 wave -> 2 blocks/CU
    gae_kernel<<<grid, 64, 0, stream>>>(rewards, values, out);
}